// Round 2
// baseline (749.805 us; speedup 1.0000x reference)
//
#include <hip/hip_runtime.h>
#include <math.h>

#define HH 128
#define WW 128
#define CC 64
#define BB 8
#define OC 64
#define OFFC 18
#define HW (HH*WW)

// ws layout (floats):
//   [0)        offs:   B*18*H*W = 2359296
//   [2359296)  wT_reg: 576*64   = 36864   (wT_reg[kidx*64+o] = w_reg[o*576+kidx])
//   [2396160)  wT_off: 64*18*9  = 10368   (wT_off[(c*18+o)*9+t] = w_off[(o*64+c)*9+t])
#define OFFS_OFF   0
#define WTREG_OFF  2359296
#define WTOFF_OFF  2396160

__global__ __launch_bounds__(256) void transpose_weights_kernel(
    const float* __restrict__ w_reg, const float* __restrict__ w_off,
    float* __restrict__ wT_reg, float* __restrict__ wT_off)
{
    int i = blockIdx.x * 256 + threadIdx.x;
    if (i < 576 * 64) {
        int kidx = i >> 6, o = i & 63;
        wT_reg[i] = w_reg[o * 576 + kidx];
    }
    if (i < CC * OFFC * 9) {
        int t = i % 9;
        int r = i / 9;          // r = c*18 + o
        int o = r % OFFC;
        int c = r / OFFC;
        wT_off[i] = w_off[(o * CC + c) * 9 + t];
    }
}

// Block = 256 threads = 64 pixels x 4 channel-groups (16 ch each).
// Grid = 8 images x 256 pixel-blocks; img = blockIdx & 7 pins image->XCD.
// 32 waves/CU occupancy (vs 8 before).
__global__ __launch_bounds__(256, 8) void offset_conv_kernel(
    const float* __restrict__ x, const float* __restrict__ wT_off,
    const float* __restrict__ b_off, float* __restrict__ offs)
{
    int img = blockIdx.x & 7;
    int pb  = blockIdx.x >> 3;           // 0..255
    int lane = threadIdx.x & 63;         // pixel within block
    int cq   = threadIdx.x >> 6;         // channel group 0..3
    int pix  = pb * 64 + lane;           // 0..16383
    int wv = pix & (WW - 1);
    int hv = pix >> 7;

    float acc[OFFC];
    #pragma unroll
    for (int o = 0; o < OFFC; ++o) acc[o] = 0.0f;

    const float* xb = x + img * (CC * HW);
    for (int ci = 0; ci < 16; ++ci) {
        int c = cq * 16 + ci;
        const float* xc = xb + c * HW;
        float v[9];
        #pragma unroll
        for (int t = 0; t < 9; ++t) {
            int dy = t / 3 - 1, dx = t % 3 - 1;
            int yy = hv + dy, xx = wv + dx;
            bool ok = (yy >= 0) && (yy < HH) && (xx >= 0) && (xx < WW);
            v[t] = ok ? xc[yy * WW + xx] : 0.0f;
        }
        const float* wc = wT_off + c * (OFFC * 9);   // wave-uniform
        #pragma unroll
        for (int o = 0; o < OFFC; ++o) {
            #pragma unroll
            for (int t = 0; t < 9; ++t)
                acc[o] = fmaf(wc[o * 9 + t], v[t], acc[o]);
        }
    }

    // Reduce the 4 channel-groups via LDS: red[cq][o][pixl]
    __shared__ float red[4 * OFFC * 64];
    #pragma unroll
    for (int o = 0; o < OFFC; ++o)
        red[(cq * OFFC + o) * 64 + lane] = acc[o];
    __syncthreads();

    float* op = offs + img * (OFFC * HW) + pb * 64;
    for (int j = threadIdx.x; j < OFFC * 64; j += 256) {
        int o = j >> 6, pixl = j & 63;
        float s = red[(0 * OFFC + o) * 64 + pixl]
                + red[(1 * OFFC + o) * 64 + pixl]
                + red[(2 * OFFC + o) * 64 + pixl]
                + red[(3 * OFFC + o) * 64 + pixl];
        op[o * HW + pixl] = s + b_off[o];
    }
}

// Block = 256 threads = 256 pixels; each thread computes 32 of the 64 outputs
// (half chosen per-block so weight reads stay wave-uniform -> s_load).
// Grid = 8 images x 2 halves x 64 pixel-blocks = 1024 blocks -> 16 waves/CU.
// Taps processed in 3 groups of 3 so hoisted params fit in registers
// (12 gathers in flight per c-iteration).
__global__ __launch_bounds__(256, 4) void deform_main_kernel(
    const float* __restrict__ x, const float* __restrict__ offs,
    const float* __restrict__ wT_reg, const float* __restrict__ b_reg,
    float* __restrict__ out)
{
    int img  = blockIdx.x & 7;
    int rest = blockIdx.x >> 3;
    int half = rest & 1;
    int pblk = rest >> 1;                 // 0..63
    int pix  = pblk * 256 + threadIdx.x;  // 0..16383
    int wv = pix & (WW - 1);
    int hv = pix >> 7;

    float acc[32];
    #pragma unroll
    for (int o = 0; o < 32; ++o) acc[o] = 0.0f;

    const float* xb = x + img * (CC * HW);
    const float* ob = offs + img * (OFFC * HW) + pix;
    const float* wbase = wT_reg + half * 32;
    const float scale = 129.0f / 127.0f;

    for (int kg = 0; kg < 3; ++kg) {
        float wt[3][4];
        int   pp[3][4];
        #pragma unroll
        for (int kt = 0; kt < 3; ++kt) {
            int k = kg * 3 + kt;
            float offx = ob[(2 * k) * HW];
            float offy = ob[(2 * k + 1) * HW];
            float px = (float)wv + (float)(k % 3 - 1) + offx;
            float py = (float)hv + (float)(k / 3 - 1) + offy;
            float qx = px * scale;
            float qy = py * scale;
            float x0f = floorf(qx), y0f = floorf(qy);
            float wx1 = qx - x0f, wy1 = qy - y0f;
            float wx0 = 1.0f - wx1, wy0 = 1.0f - wy1;
            int ix0 = (int)x0f, iy0 = (int)y0f;
            int ix1 = ix0 + 1, iy1 = iy0 + 1;

            bool vx0 = (ix0 >= 1) && (ix0 <= WW);
            bool vx1 = (ix1 >= 1) && (ix1 <= WW);
            bool vy0 = (iy0 >= 1) && (iy0 <= HH);
            bool vy1 = (iy1 >= 1) && (iy1 <= HH);
            int jx0 = min(max(ix0 - 1, 0), WW - 1);
            int jx1 = min(max(ix1 - 1, 0), WW - 1);
            int jy0 = min(max(iy0 - 1, 0), HH - 1);
            int jy1 = min(max(iy1 - 1, 0), HH - 1);

            wt[kt][0] = wy0 * wx0 * ((vy0 && vx0) ? 1.0f : 0.0f);
            wt[kt][1] = wy0 * wx1 * ((vy0 && vx1) ? 1.0f : 0.0f);
            wt[kt][2] = wy1 * wx0 * ((vy1 && vx0) ? 1.0f : 0.0f);
            wt[kt][3] = wy1 * wx1 * ((vy1 && vx1) ? 1.0f : 0.0f);
            pp[kt][0] = jy0 * WW + jx0;
            pp[kt][1] = jy0 * WW + jx1;
            pp[kt][2] = jy1 * WW + jx0;
            pp[kt][3] = jy1 * WW + jx1;
        }

        for (int c = 0; c < CC; ++c) {
            const float* xc = xb + c * HW;
            float s[3];
            #pragma unroll
            for (int kt = 0; kt < 3; ++kt) {
                float v0 = xc[pp[kt][0]];
                float v1 = xc[pp[kt][1]];
                float v2 = xc[pp[kt][2]];
                float v3 = xc[pp[kt][3]];
                float sv = wt[kt][0] * v0;
                sv = fmaf(wt[kt][1], v1, sv);
                sv = fmaf(wt[kt][2], v2, sv);
                sv = fmaf(wt[kt][3], v3, sv);
                s[kt] = sv;
            }
            #pragma unroll
            for (int kt = 0; kt < 3; ++kt) {
                const float* wr = wbase + (c * 9 + kg * 3 + kt) * 64;  // wave-uniform
                #pragma unroll
                for (int o = 0; o < 32; ++o)
                    acc[o] = fmaf(wr[o], s[kt], acc[o]);
            }
        }
    }

    float* op = out + img * (OC * HW) + half * 32 * HW + pix;
    #pragma unroll
    for (int o = 0; o < 32; ++o) op[o * HW] = acc[o] + b_reg[half * 32 + o];
}

extern "C" void kernel_launch(void* const* d_in, const int* in_sizes, int n_in,
                              void* d_out, int out_size, void* d_ws, size_t ws_size,
                              hipStream_t stream) {
    const float* x     = (const float*)d_in[0];
    const float* w_off = (const float*)d_in[1];
    const float* b_off = (const float*)d_in[2];
    const float* w_reg = (const float*)d_in[3];
    const float* b_reg = (const float*)d_in[4];
    float* out = (float*)d_out;
    float* ws  = (float*)d_ws;

    float* offs   = ws + OFFS_OFF;
    float* wT_reg = ws + WTREG_OFF;
    float* wT_off = ws + WTOFF_OFF;

    transpose_weights_kernel<<<144, 256, 0, stream>>>(w_reg, w_off, wT_reg, wT_off);
    offset_conv_kernel<<<2048, 256, 0, stream>>>(x, wT_off, b_off, offs);
    deform_main_kernel<<<1024, 256, 0, stream>>>(x, offs, wT_reg, b_reg, out);
}

// Round 3
// 521.847 us; speedup vs baseline: 1.4368x; 1.4368x over previous
//
#include <hip/hip_runtime.h>
#include <math.h>

#define HH 128
#define WW 128
#define CC 64
#define BB 8
#define OC 64
#define OFFC 18
#define HW (HH*WW)
#define HP 136
#define WP 136
#define PHW (HP*WP)   /* 18496 */

// ws layout (floats):
//   P:      8*64*136*136 = 9469952   zero-padded x; valid data at [4..131][4..131],
//           row/col 3 and 132 hold the reference xp's zero ring, rest extra zeros
//   offs:   8*18*128*128 = 2359296
//   wT_reg: 576*64       = 36864     wT_reg[(c*9+k)*64+o] = w_reg[o*576 + c*9+k]
//   wT_off: 64*18*9      = 10368     wT_off[(c*18+o)*9+t] = w_off[(o*64+c)*9+t]
#define P_OFF      0
#define P_SIZE     (BB*CC*PHW)
#define OFFS_OFF   (P_OFF + P_SIZE)
#define OFFS_SIZE  (BB*OFFC*HW)
#define WTREG_OFF  (OFFS_OFF + OFFS_SIZE)
#define WTOFF_OFF  (WTREG_OFF + 576*64)

__global__ __launch_bounds__(256) void transpose_weights_kernel(
    const float* __restrict__ w_reg, const float* __restrict__ w_off,
    float* __restrict__ wT_reg, float* __restrict__ wT_off)
{
    int i = blockIdx.x * 256 + threadIdx.x;
    if (i < 576 * 64) {
        int kidx = i >> 6, o = i & 63;
        wT_reg[i] = w_reg[o * 576 + kidx];
    }
    if (i < CC * OFFC * 9) {
        int t = i % 9;
        int r = i / 9;
        int o = r % OFFC;
        int c = r / OFFC;
        wT_off[i] = w_off[(o * CC + c) * 9 + t];
    }
}

// Build zero-padded copy: P[ic][r][cc] = x[ic][r-4][cc-4] for r,cc in [4,131], else 0.
// float4 over columns (136 = 34*4); boundary float4 blocks are entirely zero.
__global__ __launch_bounds__(256) void pad_kernel(
    const float* __restrict__ x, float* __restrict__ P)
{
    int idx = blockIdx.x * 256 + threadIdx.x;     // over 8*64*136*34 = 2367488
    if (idx >= BB * CC * HP * (WP / 4)) return;
    int q  = idx % (WP / 4);
    int rc = idx / (WP / 4);
    int r  = rc % HP;
    int ic = rc / HP;                              // img*64 + c
    int cc0 = q * 4;
    float4 v = make_float4(0.f, 0.f, 0.f, 0.f);
    if (r >= 4 && r <= 131 && cc0 >= 4 && cc0 <= 128) {
        const float4* src = (const float4*)(x + ic * HW + (r - 4) * WW + (cc0 - 4));
        v = *src;
    }
    ((float4*)P)[idx] = v;
}

// Block = 256 threads = 64 pixels x 4 channel-groups (16 ch each); LDS reduce.
// Grid = 8 images x 256 pixel-blocks; img = blockIdx & 7 pins image->XCD.
// Reads padded P: no boundary branches (zero ring == conv zero padding).
__global__ __launch_bounds__(256) void offset_conv_kernel(
    const float* __restrict__ P, const float* __restrict__ wT_off,
    const float* __restrict__ b_off, float* __restrict__ offs)
{
    int img = blockIdx.x & 7;
    int pb  = blockIdx.x >> 3;           // 0..255
    int lane = threadIdx.x & 63;
    int cq   = threadIdx.x >> 6;         // 0..3
    int pix  = pb * 64 + lane;
    int wv = pix & (WW - 1);
    int hv = pix >> 7;

    float acc[OFFC];
    #pragma unroll
    for (int o = 0; o < OFFC; ++o) acc[o] = 0.0f;

    const float* Pimg = P + img * (CC * PHW);
    for (int ci = 0; ci < 16; ++ci) {
        int c = cq * 16 + ci;
        const float* rowb = Pimg + c * PHW + (hv + 4) * WP + (wv + 4);
        float v[9];
        #pragma unroll
        for (int t = 0; t < 9; ++t) {
            int dy = t / 3 - 1, dx = t % 3 - 1;
            v[t] = rowb[dy * WP + dx];
        }
        const float* wc = wT_off + c * (OFFC * 9);   // wave-uniform -> s_load
        #pragma unroll
        for (int o = 0; o < OFFC; ++o) {
            #pragma unroll
            for (int t = 0; t < 9; ++t)
                acc[o] = fmaf(wc[o * 9 + t], v[t], acc[o]);
        }
    }

    __shared__ float red[4 * OFFC * 64];
    #pragma unroll
    for (int o = 0; o < OFFC; ++o)
        red[(cq * OFFC + o) * 64 + lane] = acc[o];
    __syncthreads();

    float* op = offs + img * (OFFC * HW) + pb * 64;
    for (int j = threadIdx.x; j < OFFC * 64; j += 256) {
        int o = j >> 6, pixl = j & 63;
        float s = red[(0 * OFFC + o) * 64 + pixl]
                + red[(1 * OFFC + o) * 64 + pixl]
                + red[(2 * OFFC + o) * 64 + pixl]
                + red[(3 * OFFC + o) * 64 + pixl];
        op[o * HW + pixl] = s + b_off[o];
    }
}

// One thread per pixel, all 64 outputs (no duplicated gathers).
// Padded P removes every validity mask: corner = P[clamp(iy0+3)][clamp(ix0+3)],
// zero ring reproduces the reference's clip+mask semantics exactly.
// Grid = 8 images x 64 pixel-blocks = 512 blocks; img = blockIdx & 7.
__global__ __launch_bounds__(256) void deform_main_kernel(
    const float* __restrict__ P, const float* __restrict__ offs,
    const float* __restrict__ wT_reg, const float* __restrict__ b_reg,
    float* __restrict__ out)
{
    int img  = blockIdx.x & 7;
    int pblk = blockIdx.x >> 3;           // 0..63
    int pix  = pblk * 256 + threadIdx.x;
    int wv = pix & (WW - 1);
    int hv = pix >> 7;

    float acc[OC];
    #pragma unroll
    for (int o = 0; o < OC; ++o) acc[o] = 0.0f;

    const float* Pimg = P + img * (CC * PHW);
    const float* ob   = offs + img * (OFFC * HW) + pix;
    const float scale = 129.0f / 127.0f;

    for (int kg = 0; kg < 3; ++kg) {
        float wt[3][4];
        int   pr[3][2];                    // p00, p10 (p01=p00+1, p11=p10+1)
        #pragma unroll
        for (int kt = 0; kt < 3; ++kt) {
            int k = kg * 3 + kt;
            float offx = ob[(2 * k) * HW];
            float offy = ob[(2 * k + 1) * HW];
            float px = (float)wv + (float)(k % 3 - 1) + offx;
            float py = (float)hv + (float)(k / 3 - 1) + offy;
            float qx = fminf(fmaxf(px * scale, -100.0f), 300.0f);
            float qy = fminf(fmaxf(py * scale, -100.0f), 300.0f);
            float x0f = floorf(qx), y0f = floorf(qy);
            float wx1 = qx - x0f, wy1 = qy - y0f;
            float wx0 = 1.0f - wx1, wy0 = 1.0f - wy1;
            int ix0 = (int)x0f, iy0 = (int)y0f;

            int c0 = min(max(ix0 + 3, 0), WP - 2);       // cols c0, c0+1
            int r0 = min(max(iy0 + 3, 0), HP - 1);
            int r1 = min(max(iy0 + 4, 0), HP - 1);

            wt[kt][0] = wy0 * wx0;
            wt[kt][1] = wy0 * wx1;
            wt[kt][2] = wy1 * wx0;
            wt[kt][3] = wy1 * wx1;
            pr[kt][0] = r0 * WP + c0;
            pr[kt][1] = r1 * WP + c0;
        }

        #pragma unroll 2
        for (int c = 0; c < CC; ++c) {
            const float* xc = Pimg + c * PHW;
            float s[3];
            #pragma unroll
            for (int kt = 0; kt < 3; ++kt) {
                float v00 = xc[pr[kt][0]];
                float v01 = xc[pr[kt][0] + 1];
                float v10 = xc[pr[kt][1]];
                float v11 = xc[pr[kt][1] + 1];
                float sv = wt[kt][0] * v00;
                sv = fmaf(wt[kt][1], v01, sv);
                sv = fmaf(wt[kt][2], v10, sv);
                sv = fmaf(wt[kt][3], v11, sv);
                s[kt] = sv;
            }
            #pragma unroll
            for (int kt = 0; kt < 3; ++kt) {
                const float* wr = wT_reg + (c * 9 + kg * 3 + kt) * 64;  // wave-uniform
                #pragma unroll
                for (int o = 0; o < OC; ++o)
                    acc[o] = fmaf(wr[o], s[kt], acc[o]);
            }
        }
    }

    float* op = out + img * (OC * HW) + pix;
    #pragma unroll
    for (int o = 0; o < OC; ++o) op[o * HW] = acc[o] + b_reg[o];
}

extern "C" void kernel_launch(void* const* d_in, const int* in_sizes, int n_in,
                              void* d_out, int out_size, void* d_ws, size_t ws_size,
                              hipStream_t stream) {
    const float* x     = (const float*)d_in[0];
    const float* w_off = (const float*)d_in[1];
    const float* b_off = (const float*)d_in[2];
    const float* w_reg = (const float*)d_in[3];
    const float* b_reg = (const float*)d_in[4];
    float* out = (float*)d_out;
    float* ws  = (float*)d_ws;

    float* P      = ws + P_OFF;
    float* offs   = ws + OFFS_OFF;
    float* wT_reg = ws + WTREG_OFF;
    float* wT_off = ws + WTOFF_OFF;

    transpose_weights_kernel<<<144, 256, 0, stream>>>(w_reg, w_off, wT_reg, wT_off);
    pad_kernel<<<(BB * CC * HP * (WP / 4) + 255) / 256, 256, 0, stream>>>(x, P);
    offset_conv_kernel<<<2048, 256, 0, stream>>>(P, wT_off, b_off, offs);
    deform_main_kernel<<<512, 256, 0, stream>>>(P, offs, wT_reg, b_reg, out);
}

// Round 4
// 378.787 us; speedup vs baseline: 1.9795x; 1.3777x over previous
//
#include <hip/hip_runtime.h>
#include <math.h>

#define HH 128
#define WW 128
#define CC 64
#define BB 8
#define OC 64
#define OFFC 18
#define HW (HH*WW)
#define HP 136
#define WP 136
#define PHW (HP*WP)   /* 18496 */

// ws layout (floats):
//   P:      8*64*136*136 = 9469952   zero-padded x; valid data at [4..131][4..131]
//   offs:   8*18*128*128 = 2359296
//   wT_reg: 576*64       = 36864     wT_reg[(c*9+k)*64+o] = w_reg[o*576 + c*9+k]
//   wT_off: 64*18*9      = 10368     wT_off[(c*18+o)*9+t] = w_off[(o*64+c)*9+t]
#define P_OFF      0
#define P_SIZE     (BB*CC*PHW)
#define OFFS_OFF   (P_OFF + P_SIZE)
#define OFFS_SIZE  (BB*OFFC*HW)
#define WTREG_OFF  (OFFS_OFF + OFFS_SIZE)
#define WTOFF_OFF  (WTREG_OFF + 576*64)

__global__ __launch_bounds__(256) void transpose_weights_kernel(
    const float* __restrict__ w_reg, const float* __restrict__ w_off,
    float* __restrict__ wT_reg, float* __restrict__ wT_off)
{
    int i = blockIdx.x * 256 + threadIdx.x;
    if (i < 576 * 64) {
        int kidx = i >> 6, o = i & 63;
        wT_reg[i] = w_reg[o * 576 + kidx];
    }
    if (i < CC * OFFC * 9) {
        int t = i % 9;
        int r = i / 9;
        int o = r % OFFC;
        int c = r / OFFC;
        wT_off[i] = w_off[(o * CC + c) * 9 + t];
    }
}

// Zero-padded copy of x (float4 over columns; 136 = 34*4).
__global__ __launch_bounds__(256) void pad_kernel(
    const float* __restrict__ x, float* __restrict__ P)
{
    int idx = blockIdx.x * 256 + threadIdx.x;     // over 8*64*136*34
    if (idx >= BB * CC * HP * (WP / 4)) return;
    int q  = idx % (WP / 4);
    int rc = idx / (WP / 4);
    int r  = rc % HP;
    int ic = rc / HP;
    int cc0 = q * 4;
    float4 v = make_float4(0.f, 0.f, 0.f, 0.f);
    if (r >= 4 && r <= 131 && cc0 >= 4 && cc0 <= 128) {
        const float4* src = (const float4*)(x + ic * HW + (r - 4) * WW + (cc0 - 4));
        v = *src;
    }
    ((float4*)P)[idx] = v;
}

// Initialize out[img][o][pix] = b_reg[o] (float4 stores); deform adds into it.
__global__ __launch_bounds__(256) void bias_init_kernel(
    const float* __restrict__ b_reg, float* __restrict__ out)
{
    int idx = blockIdx.x * 256 + threadIdx.x;     // over 8*64*16384/4 = 2097152
    if (idx >= BB * OC * (HW / 4)) return;
    int o = (idx / (HW / 4)) & (OC - 1);
    float b = b_reg[o];
    ((float4*)out)[idx] = make_float4(b, b, b, b);
}

// Block = 64 px x 4 channel-groups; weight block index forced wave-uniform via
// readfirstlane so weight reads compile to s_load (R2 regression fix).
__global__ __launch_bounds__(256) void offset_conv_kernel(
    const float* __restrict__ P, const float* __restrict__ wT_off,
    const float* __restrict__ b_off, float* __restrict__ offs)
{
    int img = blockIdx.x & 7;
    int pb  = blockIdx.x >> 3;           // 0..255
    int lane = threadIdx.x & 63;
    int cq   = __builtin_amdgcn_readfirstlane(threadIdx.x >> 6);  // SGPR: 0..3
    int pix  = pb * 64 + lane;
    int wv = pix & (WW - 1);
    int hv = pix >> 7;

    float acc[OFFC];
    #pragma unroll
    for (int o = 0; o < OFFC; ++o) acc[o] = 0.0f;

    const float* Pimg = P + img * (CC * PHW);
    for (int ci = 0; ci < 16; ++ci) {
        int c = cq * 16 + ci;            // SGPR arithmetic
        const float* rowb = Pimg + c * PHW + (hv + 4) * WP + (wv + 4);
        float v[9];
        #pragma unroll
        for (int t = 0; t < 9; ++t) {
            int dy = t / 3 - 1, dx = t % 3 - 1;
            v[t] = rowb[dy * WP + dx];
        }
        const float* wc = wT_off + c * (OFFC * 9);   // SGPR base -> s_load
        #pragma unroll
        for (int o = 0; o < OFFC; ++o) {
            #pragma unroll
            for (int t = 0; t < 9; ++t)
                acc[o] = fmaf(wc[o * 9 + t], v[t], acc[o]);
        }
    }

    __shared__ float red[4 * OFFC * 64];
    #pragma unroll
    for (int o = 0; o < OFFC; ++o)
        red[(cq * OFFC + o) * 64 + lane] = acc[o];
    __syncthreads();

    float* op = offs + img * (OFFC * HW) + pb * 64;
    for (int j = threadIdx.x; j < OFFC * 64; j += 256) {
        int o = j >> 6, pixl = j & 63;
        float s = red[(0 * OFFC + o) * 64 + pixl]
                + red[(1 * OFFC + o) * 64 + pixl]
                + red[(2 * OFFC + o) * 64 + pixl]
                + red[(3 * OFFC + o) * 64 + pixl];
        op[o * HW + pixl] = s + b_off[o];
    }
}

// One thread per pixel, but work split 6 ways per pixel across blocks:
// (output half: 2) x (tap triple: 3). acc[32] keeps VGPR<=64 so 8 blocks/CU
// resident -> 32 waves/CU (R3 was grid-capped at 8 waves/CU, VALUBusy 27%).
// Tap-partials accumulate into bias-initialized out via device-scope atomics.
__global__ __launch_bounds__(256) void deform_main_kernel(
    const float* __restrict__ P, const float* __restrict__ offs,
    const float* __restrict__ wT_reg, float* __restrict__ out)
{
    int img  = blockIdx.x & 7;
    int rest = blockIdx.x >> 3;
    int sub  = rest % 6;                  // 0..5
    int pblk = rest / 6;                  // 0..63
    int half = sub & 1;
    int kg   = sub >> 1;                  // 0..2
    int pix  = pblk * 256 + threadIdx.x;
    int wv = pix & (WW - 1);
    int hv = pix >> 7;

    float acc[32];
    #pragma unroll
    for (int o = 0; o < 32; ++o) acc[o] = 0.0f;

    const float* Pimg  = P + img * (CC * PHW);
    const float* ob    = offs + img * (OFFC * HW) + pix;
    const float* wbase = wT_reg + half * 32;
    const float scale = 129.0f / 127.0f;

    float wt[3][4];
    int   pr[3][2];                        // p00, p10 (p01=p00+1, p11=p10+1)
    #pragma unroll
    for (int kt = 0; kt < 3; ++kt) {
        int k = kg * 3 + kt;
        float offx = ob[(2 * k) * HW];
        float offy = ob[(2 * k + 1) * HW];
        float px = (float)wv + (float)(k % 3 - 1) + offx;
        float py = (float)hv + (float)(k / 3 - 1) + offy;
        float qx = fminf(fmaxf(px * scale, -100.0f), 300.0f);
        float qy = fminf(fmaxf(py * scale, -100.0f), 300.0f);
        float x0f = floorf(qx), y0f = floorf(qy);
        float wx1 = qx - x0f, wy1 = qy - y0f;
        float wx0 = 1.0f - wx1, wy0 = 1.0f - wy1;
        int ix0 = (int)x0f, iy0 = (int)y0f;

        int c0 = min(max(ix0 + 3, 0), WP - 2);
        int r0 = min(max(iy0 + 3, 0), HP - 1);
        int r1 = min(max(iy0 + 4, 0), HP - 1);

        wt[kt][0] = wy0 * wx0;
        wt[kt][1] = wy0 * wx1;
        wt[kt][2] = wy1 * wx0;
        wt[kt][3] = wy1 * wx1;
        pr[kt][0] = r0 * WP + c0;
        pr[kt][1] = r1 * WP + c0;
    }

    #pragma unroll 2
    for (int c = 0; c < CC; ++c) {
        const float* xc = Pimg + c * PHW;
        float s[3];
        #pragma unroll
        for (int kt = 0; kt < 3; ++kt) {
            float v00 = xc[pr[kt][0]];
            float v01 = xc[pr[kt][0] + 1];
            float v10 = xc[pr[kt][1]];
            float v11 = xc[pr[kt][1] + 1];
            float sv = wt[kt][0] * v00;
            sv = fmaf(wt[kt][1], v01, sv);
            sv = fmaf(wt[kt][2], v10, sv);
            sv = fmaf(wt[kt][3], v11, sv);
            s[kt] = sv;
        }
        #pragma unroll
        for (int kt = 0; kt < 3; ++kt) {
            const float* wr = wbase + (c * 9 + kg * 3 + kt) * 64;  // wave-uniform
            #pragma unroll
            for (int o = 0; o < 32; ++o)
                acc[o] = fmaf(wr[o], s[kt], acc[o]);
        }
    }

    float* op = out + img * (OC * HW) + half * 32 * HW + pix;
    #pragma unroll
    for (int o = 0; o < 32; ++o)
        atomicAdd(&op[o * HW], acc[o]);
}

extern "C" void kernel_launch(void* const* d_in, const int* in_sizes, int n_in,
                              void* d_out, int out_size, void* d_ws, size_t ws_size,
                              hipStream_t stream) {
    const float* x     = (const float*)d_in[0];
    const float* w_off = (const float*)d_in[1];
    const float* b_off = (const float*)d_in[2];
    const float* w_reg = (const float*)d_in[3];
    const float* b_reg = (const float*)d_in[4];
    float* out = (float*)d_out;
    float* ws  = (float*)d_ws;

    float* P      = ws + P_OFF;
    float* offs   = ws + OFFS_OFF;
    float* wT_reg = ws + WTREG_OFF;
    float* wT_off = ws + WTOFF_OFF;

    transpose_weights_kernel<<<144, 256, 0, stream>>>(w_reg, w_off, wT_reg, wT_off);
    pad_kernel<<<(BB * CC * HP * (WP / 4) + 255) / 256, 256, 0, stream>>>(x, P);
    bias_init_kernel<<<(BB * OC * (HW / 4) + 255) / 256, 256, 0, stream>>>(b_reg, out);
    offset_conv_kernel<<<2048, 256, 0, stream>>>(P, wT_off, b_off, offs);
    deform_main_kernel<<<3072, 256, 0, stream>>>(P, offs, wT_reg, out);
}

// Round 5
// 372.785 us; speedup vs baseline: 2.0114x; 1.0161x over previous
//
#include <hip/hip_runtime.h>
#include <math.h>

#define HH 128
#define WW 128
#define CC 64
#define BB 8
#define OC 64
#define OFFC 18
#define HW (HH*WW)
#define HP 136
#define WP 136
#define PHW (HP*WP)   /* 18496 */

// ws layout (floats):
//   P4:     8 img * 16 quads * 136*136 * 4ch = 9469952 floats (channel-interleaved:
//           float4 at [(img*16+q)*PHW + r*WP + col] holds channels 4q..4q+3)
//   offs:   8*18*128*128 = 2359296
//   wT_reg: 576*64       = 36864   wT_reg[(c*9+k)*64+o] = w_reg[o*576 + c*9+k]
//   wT_off: 64*18*9      = 10368   wT_off[(c*18+o)*9+t] = w_off[(o*64+c)*9+t]
#define P_OFF      0
#define P_SIZE     (BB*CC*PHW)
#define OFFS_OFF   (P_OFF + P_SIZE)
#define OFFS_SIZE  (BB*OFFC*HW)
#define WTREG_OFF  (OFFS_OFF + OFFS_SIZE)
#define WTOFF_OFF  (WTREG_OFF + 576*64)

__global__ __launch_bounds__(256) void transpose_weights_kernel(
    const float* __restrict__ w_reg, const float* __restrict__ w_off,
    float* __restrict__ wT_reg, float* __restrict__ wT_off)
{
    int i = blockIdx.x * 256 + threadIdx.x;
    if (i < 576 * 64) {
        int kidx = i >> 6, o = i & 63;
        wT_reg[i] = w_reg[o * 576 + kidx];
    }
    if (i < CC * OFFC * 9) {
        int t = i % 9;
        int r = i / 9;
        int o = r % OFFC;
        int c = r / OFFC;
        wT_off[i] = w_off[(o * CC + c) * 9 + t];
    }
}

// Build channel-interleaved zero-padded P4: one thread per (img,quad,r,col)
// writes float4 {x[4q],x[4q+1],x[4q+2],x[4q+3]} at that padded position.
__global__ __launch_bounds__(256) void pad_kernel(
    const float* __restrict__ x, float* __restrict__ P)
{
    int idx = blockIdx.x * 256 + threadIdx.x;     // over 8*16*PHW = 2367488
    if (idx >= BB * 16 * PHW) return;
    int pos = idx % PHW;
    int qc  = idx / PHW;          // img*16 + q
    int r   = pos / WP;
    int col = pos % WP;
    float4 v = make_float4(0.f, 0.f, 0.f, 0.f);
    if (r >= 4 && r <= 131 && col >= 4 && col <= 131) {
        const float* src = x + (qc * 4) * HW + (r - 4) * WW + (col - 4);
        v.x = src[0];
        v.y = src[HW];
        v.z = src[2 * HW];
        v.w = src[3 * HW];
    }
    ((float4*)P)[idx] = v;
}

// out[img][o][pix] = b_reg[o]; deform atomically adds partials into it.
__global__ __launch_bounds__(256) void bias_init_kernel(
    const float* __restrict__ b_reg, float* __restrict__ out)
{
    int idx = blockIdx.x * 256 + threadIdx.x;     // over 8*64*16384/4
    if (idx >= BB * OC * (HW / 4)) return;
    int o = (idx / (HW / 4)) & (OC - 1);
    float b = b_reg[o];
    ((float4*)out)[idx] = make_float4(b, b, b, b);
}

// Block = 64 px x 4 channel-groups (16ch = 4 quads each); float4 channel loads.
// Weight indices forced wave-uniform (readfirstlane) -> s_load.
__global__ __launch_bounds__(256) void offset_conv_kernel(
    const float* __restrict__ P, const float* __restrict__ wT_off,
    const float* __restrict__ b_off, float* __restrict__ offs)
{
    int img = blockIdx.x & 7;
    int pb  = blockIdx.x >> 3;           // 0..255
    int lane = threadIdx.x & 63;
    int cq   = __builtin_amdgcn_readfirstlane(threadIdx.x >> 6);  // 0..3
    int pix  = pb * 64 + lane;
    int wv = pix & (WW - 1);
    int hv = pix >> 7;

    float acc[OFFC];
    #pragma unroll
    for (int o = 0; o < OFFC; ++o) acc[o] = 0.0f;

    const float4* P4 = (const float4*)P;
    for (int qi = 0; qi < 4; ++qi) {
        int q = cq * 4 + qi;             // SGPR
        const float4* base = P4 + (img * 16 + q) * PHW + (hv + 4) * WP + (wv + 4);
        float4 v[9];
        #pragma unroll
        for (int t = 0; t < 9; ++t) {
            int dy = t / 3 - 1, dx = t % 3 - 1;
            v[t] = base[dy * WP + dx];
        }
        #pragma unroll
        for (int cl = 0; cl < 4; ++cl) {
            int c = q * 4 + cl;
            const float* wc = wT_off + c * (OFFC * 9);   // uniform -> s_load
            #pragma unroll
            for (int o = 0; o < OFFC; ++o) {
                float a = acc[o];
                #pragma unroll
                for (int t = 0; t < 9; ++t) {
                    const float* vp = (const float*)&v[t];
                    a = fmaf(wc[o * 9 + t], vp[cl], a);
                }
                acc[o] = a;
            }
        }
    }

    __shared__ float red[4 * OFFC * 64];
    #pragma unroll
    for (int o = 0; o < OFFC; ++o)
        red[(cq * OFFC + o) * 64 + lane] = acc[o];
    __syncthreads();

    float* op = offs + img * (OFFC * HW) + pb * 64;
    for (int j = threadIdx.x; j < OFFC * 64; j += 256) {
        int o = j >> 6, pixl = j & 63;
        float s = red[(0 * OFFC + o) * 64 + pixl]
                + red[(1 * OFFC + o) * 64 + pixl]
                + red[(2 * OFFC + o) * 64 + pixl]
                + red[(3 * OFFC + o) * 64 + pixl];
        op[o * HW + pixl] = s + b_off[o];
    }
}

// One thread per pixel, all 64 outputs, channels split in half across blocks
// (no gather duplication). float4 gathers fetch 4 channels per corner ->
// 4x fewer VMEM instructions than R4 (the measured bottleneck).
// Grid = 8 img x 2 c-halves x 64 pixel-blocks = 1024 blocks.
__global__ __launch_bounds__(256) void deform_main_kernel(
    const float* __restrict__ P, const float* __restrict__ offs,
    const float* __restrict__ wT_reg, float* __restrict__ out)
{
    int img  = blockIdx.x & 7;
    int rest = blockIdx.x >> 3;
    int half = rest & 1;
    int pblk = rest >> 1;                 // 0..63
    int pix  = pblk * 256 + threadIdx.x;
    int wv = pix & (WW - 1);
    int hv = pix >> 7;

    float acc[OC];
    #pragma unroll
    for (int o = 0; o < OC; ++o) acc[o] = 0.0f;

    const float4* P4 = (const float4*)P;
    const float* ob  = offs + img * (OFFC * HW) + pix;
    const float scale = 129.0f / 127.0f;

    for (int kg = 0; kg < 3; ++kg) {
        float wt[3][4];
        int   pr[3][2];                    // float4-unit offsets of (r0,c0),(r1,c0)
        #pragma unroll
        for (int kt = 0; kt < 3; ++kt) {
            int k = kg * 3 + kt;
            float offx = ob[(2 * k) * HW];
            float offy = ob[(2 * k + 1) * HW];
            float px = (float)wv + (float)(k % 3 - 1) + offx;
            float py = (float)hv + (float)(k / 3 - 1) + offy;
            float qx = fminf(fmaxf(px * scale, -100.0f), 300.0f);
            float qy = fminf(fmaxf(py * scale, -100.0f), 300.0f);
            float x0f = floorf(qx), y0f = floorf(qy);
            float wx1 = qx - x0f, wy1 = qy - y0f;
            float wx0 = 1.0f - wx1, wy0 = 1.0f - wy1;
            int ix0 = (int)x0f, iy0 = (int)y0f;

            int c0 = min(max(ix0 + 3, 0), WP - 2);
            int r0 = min(max(iy0 + 3, 0), HP - 1);
            int r1 = min(max(iy0 + 4, 0), HP - 1);

            wt[kt][0] = wy0 * wx0;
            wt[kt][1] = wy0 * wx1;
            wt[kt][2] = wy1 * wx0;
            wt[kt][3] = wy1 * wx1;
            pr[kt][0] = r0 * WP + c0;
            pr[kt][1] = r1 * WP + c0;
        }

        for (int qi = 0; qi < 8; ++qi) {
            int q = half * 8 + qi;                       // quad = channels 4q..4q+3
            const float4* xq = P4 + (img * 16 + q) * PHW;
            #pragma unroll
            for (int kt = 0; kt < 3; ++kt) {
                int k = kg * 3 + kt;
                float4 v00 = xq[pr[kt][0]];
                float4 v01 = xq[pr[kt][0] + 1];
                float4 v10 = xq[pr[kt][1]];
                float4 v11 = xq[pr[kt][1] + 1];
                float s0 = wt[kt][0] * v00.x; s0 = fmaf(wt[kt][1], v01.x, s0);
                s0 = fmaf(wt[kt][2], v10.x, s0); s0 = fmaf(wt[kt][3], v11.x, s0);
                float s1 = wt[kt][0] * v00.y; s1 = fmaf(wt[kt][1], v01.y, s1);
                s1 = fmaf(wt[kt][2], v10.y, s1); s1 = fmaf(wt[kt][3], v11.y, s1);
                float s2 = wt[kt][0] * v00.z; s2 = fmaf(wt[kt][1], v01.z, s2);
                s2 = fmaf(wt[kt][2], v10.z, s2); s2 = fmaf(wt[kt][3], v11.z, s2);
                float s3 = wt[kt][0] * v00.w; s3 = fmaf(wt[kt][1], v01.w, s3);
                s3 = fmaf(wt[kt][2], v10.w, s3); s3 = fmaf(wt[kt][3], v11.w, s3);

                const float* wr0 = wT_reg + ((q * 4 + 0) * 9 + k) * 64;  // uniform
                const float* wr1 = wT_reg + ((q * 4 + 1) * 9 + k) * 64;
                const float* wr2 = wT_reg + ((q * 4 + 2) * 9 + k) * 64;
                const float* wr3 = wT_reg + ((q * 4 + 3) * 9 + k) * 64;
                #pragma unroll
                for (int o = 0; o < OC; ++o) {
                    float a = acc[o];
                    a = fmaf(wr0[o], s0, a);
                    a = fmaf(wr1[o], s1, a);
                    a = fmaf(wr2[o], s2, a);
                    a = fmaf(wr3[o], s3, a);
                    acc[o] = a;
                }
            }
        }
    }

    float* op = out + img * (OC * HW) + pix;
    #pragma unroll
    for (int o = 0; o < OC; ++o)
        atomicAdd(&op[o * HW], acc[o]);
}

extern "C" void kernel_launch(void* const* d_in, const int* in_sizes, int n_in,
                              void* d_out, int out_size, void* d_ws, size_t ws_size,
                              hipStream_t stream) {
    const float* x     = (const float*)d_in[0];
    const float* w_off = (const float*)d_in[1];
    const float* b_off = (const float*)d_in[2];
    const float* w_reg = (const float*)d_in[3];
    const float* b_reg = (const float*)d_in[4];
    float* out = (float*)d_out;
    float* ws  = (float*)d_ws;

    float* P      = ws + P_OFF;
    float* offs   = ws + OFFS_OFF;
    float* wT_reg = ws + WTREG_OFF;
    float* wT_off = ws + WTOFF_OFF;

    transpose_weights_kernel<<<144, 256, 0, stream>>>(w_reg, w_off, wT_reg, wT_off);
    pad_kernel<<<(BB * 16 * PHW + 255) / 256, 256, 0, stream>>>(x, P);
    bias_init_kernel<<<(BB * OC * (HW / 4) + 255) / 256, 256, 0, stream>>>(b_reg, out);
    offset_conv_kernel<<<2048, 256, 0, stream>>>(P, wT_off, b_off, offs);
    deform_main_kernel<<<1024, 256, 0, stream>>>(P, offs, wT_reg, out);
}

// Round 6
// 207.215 us; speedup vs baseline: 3.6185x; 1.7990x over previous
//
#include <hip/hip_runtime.h>
#include <math.h>

#define HH 128
#define WW 128
#define CC 64
#define BB 8
#define OC 64
#define OFFC 18
#define HW (HH*WW)
#define HP 136
#define WP 136
#define PHW (HP*WP)   /* 18496 */

typedef __attribute__((ext_vector_type(8))) short bf16x8;
typedef __attribute__((ext_vector_type(4))) float f32x4;

// ws layout (floats):
//   P4:     8*16*PHW*4 = 9469952  channel-interleaved zero-padded x
//   offs:   8*18*128*128 = 2359296
//   wA_reg: 36864 bf16 (18432 fl) A-frag layout [(tap*2+kk)*64+o][quad][8j]
//           = bf16(w_reg[o][c*9+tap]), c = kk*32+quad*8+j
//   wA_off: 18432 bf16 (9216 fl)  [(tap*2+kk)*32+o][quad][8j], rows 18..31 zero
#define P_OFF      0
#define P_SIZE     (BB*CC*PHW)
#define OFFS_OFF   (P_OFF + P_SIZE)
#define OFFS_SIZE  (BB*OFFC*HW)
#define WAREG_OFF  (OFFS_OFF + OFFS_SIZE)
#define WAREG_SIZE 18432
#define WAOFF_OFF  (WAREG_OFF + WAREG_SIZE)

__device__ __forceinline__ unsigned bf16rne(float f) {
    unsigned u = __float_as_uint(f);
    return (u + 0x7FFFu + ((u >> 16) & 1u)) >> 16;
}
__device__ __forceinline__ unsigned pack2(float a, float b) {
    return bf16rne(a) | (bf16rne(b) << 16);
}

// Pre-transpose both weight matrices into MFMA A-fragment order, bf16.
__global__ __launch_bounds__(256) void prep_kernel(
    const float* __restrict__ w_reg, const float* __restrict__ w_off,
    unsigned short* __restrict__ wA_reg, unsigned short* __restrict__ wA_off)
{
    int i = blockIdx.x * 256 + threadIdx.x;
    if (i < 18 * 64 * 32) {                    // 36864
        int j = i & 7, quad = (i >> 3) & 3, o = (i >> 5) & 63, ks = i >> 11;
        int kt = ks >> 1, kk = ks & 1;
        int c = kk * 32 + quad * 8 + j;
        wA_reg[i] = (unsigned short)bf16rne(w_reg[o * 576 + c * 9 + kt]);
    }
    if (i < 18 * 32 * 32) {                    // 18432
        int j = i & 7, quad = (i >> 3) & 3, o = (i >> 5) & 31, ks = i >> 10;
        int kt = ks >> 1, kk = ks & 1;
        int c = kk * 32 + quad * 8 + j;
        float v = (o < OFFC) ? w_off[(o * CC + c) * 9 + kt] : 0.0f;
        wA_off[i] = (unsigned short)bf16rne(v);
    }
}

// Channel-interleaved zero-padded P4 (as R5).
__global__ __launch_bounds__(256) void pad_kernel(
    const float* __restrict__ x, float* __restrict__ P)
{
    int idx = blockIdx.x * 256 + threadIdx.x;     // over 8*16*PHW
    if (idx >= BB * 16 * PHW) return;
    int pos = idx % PHW;
    int qc  = idx / PHW;
    int r   = pos / WP;
    int col = pos % WP;
    float4 v = make_float4(0.f, 0.f, 0.f, 0.f);
    if (r >= 4 && r <= 131 && col >= 4 && col <= 131) {
        const float* src = x + (qc * 4) * HW + (r - 4) * WW + (col - 4);
        v.x = src[0];
        v.y = src[HW];
        v.z = src[2 * HW];
        v.w = src[3 * HW];
    }
    ((float4*)P)[idx] = v;
}

// Offset conv as fused stage+MFMA. Block = 256 thr = one 128-px row.
// Taps are integer shifts: 1 float4 load per quad per tap -> LDS bf16 tile
// [c8][px][8] -> 4 waves x mfma 16x16x32 (M=32, rows 18..31 padded zero).
__global__ __launch_bounds__(256) void offset_conv_kernel(
    const float* __restrict__ P, const unsigned short* __restrict__ wA_off,
    const float* __restrict__ b_off, float* __restrict__ offs)
{
    __shared__ uint2 xs[2048];                 // 16 KB: [c8(8)][px(128)] x 16B
    int img  = blockIdx.x & 7;
    int pblk = blockIdx.x >> 3;                // 0..127 = row
    int tid  = threadIdx.x;
    int px   = tid & 127;
    int qb   = (tid >> 7) * 8;                 // quads 0-7 / 8-15
    int hv = pblk, wv = px;
    const float4* P4 = (const float4*)P + img * 16 * PHW;
    const bf16x8* wAv = (const bf16x8*)wA_off;
    int lane = tid & 63;
    int wvid = tid >> 6;                       // wave 0..3
    int s  = wvid & 1;                         // o-strip (0:o0-15, 1:o16-31)
    int ph = wvid >> 1;                        // px half

    f32x4 acc[4];
    #pragma unroll
    for (int pt = 0; pt < 4; ++pt) acc[pt] = (f32x4){0.f, 0.f, 0.f, 0.f};

    for (int tap = 0; tap < 9; ++tap) {
        int dy = tap / 3 - 1, dx = tap % 3 - 1;
        int pos = (hv + 4 + dy) * WP + (wv + 4 + dx);
        #pragma unroll 4
        for (int qi = 0; qi < 8; ++qi) {
            int q = qb + qi;
            float4 v = P4[q * PHW + pos];
            xs[((q >> 1) * 128 + px) * 2 + (q & 1)] =
                make_uint2(pack2(v.x, v.y), pack2(v.z, v.w));
        }
        __syncthreads();
        bf16x8 a0 = wAv[((tap * 2 + 0) * 32 + s * 16 + (lane & 15)) * 4 + (lane >> 4)];
        bf16x8 a1 = wAv[((tap * 2 + 1) * 32 + s * 16 + (lane & 15)) * 4 + (lane >> 4)];
        const bf16x8* xsv = (const bf16x8*)xs;
        #pragma unroll
        for (int pt = 0; pt < 4; ++pt) {
            int pxl = ph * 64 + pt * 16 + (lane & 15);
            bf16x8 b0 = xsv[(lane >> 4) * 128 + pxl];
            acc[pt] = __builtin_amdgcn_mfma_f32_16x16x32_bf16(a0, b0, acc[pt], 0, 0, 0);
            bf16x8 b1 = xsv[(4 + (lane >> 4)) * 128 + pxl];
            acc[pt] = __builtin_amdgcn_mfma_f32_16x16x32_bf16(a1, b1, acc[pt], 0, 0, 0);
        }
        __syncthreads();
    }

    float* ob = offs + img * (OFFC * HW) + pblk * 128;
    #pragma unroll
    for (int r = 0; r < 4; ++r) {
        int o = s * 16 + (lane >> 4) * 4 + r;
        if (o < OFFC) {
            float bias = b_off[o];
            #pragma unroll
            for (int pt = 0; pt < 4; ++pt) {
                int pxl = ph * 64 + pt * 16 + (lane & 15);
                ob[o * HW + pxl] = acc[pt][r] + bias;
            }
        }
    }
}

// Deformable sampling + 64x576 GEMM, fused stage+MFMA.
// Block = 256 thr = one 128-px row; per tap: bilinear-sample 64 channels to
// LDS bf16 tile [c8][px][8], then 4 waves (o-strips of 16) x 16 MFMA.
__global__ __launch_bounds__(256) void deform_main_kernel(
    const float* __restrict__ P, const float* __restrict__ offs,
    const unsigned short* __restrict__ wA_reg, const float* __restrict__ b_reg,
    float* __restrict__ out)
{
    __shared__ uint2 xs[2048];                 // 16 KB
    int img  = blockIdx.x & 7;
    int pblk = blockIdx.x >> 3;                // 0..127 = row
    int tid  = threadIdx.x;
    int px   = tid & 127;
    int qb   = (tid >> 7) * 8;
    int hv = pblk, wv = px;
    const float4* P4 = (const float4*)P + img * 16 * PHW;
    const float*  obf = offs + img * (OFFC * HW) + pblk * 128 + px;
    const bf16x8* wAv = (const bf16x8*)wA_reg;
    int lane = tid & 63;
    int wvid = tid >> 6;                       // o-strip = wvid*16
    const float scale = 129.0f / 127.0f;

    f32x4 acc[8];
    #pragma unroll
    for (int pt = 0; pt < 8; ++pt) acc[pt] = (f32x4){0.f, 0.f, 0.f, 0.f};

    for (int tap = 0; tap < 9; ++tap) {
        float offx = obf[(2 * tap) * HW];
        float offy = obf[(2 * tap + 1) * HW];
        float pxf = (float)wv + (float)(tap % 3 - 1) + offx;
        float pyf = (float)hv + (float)(tap / 3 - 1) + offy;
        float qx = fminf(fmaxf(pxf * scale, -100.0f), 300.0f);
        float qy = fminf(fmaxf(pyf * scale, -100.0f), 300.0f);
        float x0f = floorf(qx), y0f = floorf(qy);
        float wx1 = qx - x0f, wy1 = qy - y0f;
        float wx0 = 1.0f - wx1, wy0 = 1.0f - wy1;
        int ix0 = (int)x0f, iy0 = (int)y0f;
        int c0 = min(max(ix0 + 3, 0), WP - 2);
        int r0 = min(max(iy0 + 3, 0), HP - 1);
        int r1 = min(max(iy0 + 4, 0), HP - 1);
        float w00 = wy0 * wx0, w01 = wy0 * wx1;
        float w10 = wy1 * wx0, w11 = wy1 * wx1;
        int pr0 = r0 * WP + c0, pr1 = r1 * WP + c0;

        #pragma unroll 2
        for (int qi = 0; qi < 8; ++qi) {
            int q = qb + qi;
            const float4* xq = P4 + q * PHW;
            float4 v00 = xq[pr0];
            float4 v01 = xq[pr0 + 1];
            float4 v10 = xq[pr1];
            float4 v11 = xq[pr1 + 1];
            float s0 = w00 * v00.x; s0 = fmaf(w01, v01.x, s0);
            s0 = fmaf(w10, v10.x, s0); s0 = fmaf(w11, v11.x, s0);
            float s1 = w00 * v00.y; s1 = fmaf(w01, v01.y, s1);
            s1 = fmaf(w10, v10.y, s1); s1 = fmaf(w11, v11.y, s1);
            float s2 = w00 * v00.z; s2 = fmaf(w01, v01.z, s2);
            s2 = fmaf(w10, v10.z, s2); s2 = fmaf(w11, v11.z, s2);
            float s3 = w00 * v00.w; s3 = fmaf(w01, v01.w, s3);
            s3 = fmaf(w10, v10.w, s3); s3 = fmaf(w11, v11.w, s3);
            xs[((q >> 1) * 128 + px) * 2 + (q & 1)] =
                make_uint2(pack2(s0, s1), pack2(s2, s3));
        }
        __syncthreads();
        bf16x8 a0 = wAv[((tap * 2 + 0) * 64 + wvid * 16 + (lane & 15)) * 4 + (lane >> 4)];
        bf16x8 a1 = wAv[((tap * 2 + 1) * 64 + wvid * 16 + (lane & 15)) * 4 + (lane >> 4)];
        const bf16x8* xsv = (const bf16x8*)xs;
        #pragma unroll
        for (int pt = 0; pt < 8; ++pt) {
            int pxl = pt * 16 + (lane & 15);
            bf16x8 b0 = xsv[(lane >> 4) * 128 + pxl];
            acc[pt] = __builtin_amdgcn_mfma_f32_16x16x32_bf16(a0, b0, acc[pt], 0, 0, 0);
            bf16x8 b1 = xsv[(4 + (lane >> 4)) * 128 + pxl];
            acc[pt] = __builtin_amdgcn_mfma_f32_16x16x32_bf16(a1, b1, acc[pt], 0, 0, 0);
        }
        __syncthreads();
    }

    float* op = out + img * (OC * HW) + pblk * 128;
    #pragma unroll
    for (int r = 0; r < 4; ++r) {
        int o = wvid * 16 + (lane >> 4) * 4 + r;
        float bias = b_reg[o];
        #pragma unroll
        for (int pt = 0; pt < 8; ++pt) {
            int pxl = pt * 16 + (lane & 15);
            op[o * HW + pxl] = acc[pt][r] + bias;
        }
    }
}

extern "C" void kernel_launch(void* const* d_in, const int* in_sizes, int n_in,
                              void* d_out, int out_size, void* d_ws, size_t ws_size,
                              hipStream_t stream) {
    const float* x     = (const float*)d_in[0];
    const float* w_off = (const float*)d_in[1];
    const float* b_off = (const float*)d_in[2];
    const float* w_reg = (const float*)d_in[3];
    const float* b_reg = (const float*)d_in[4];
    float* out = (float*)d_out;
    float* ws  = (float*)d_ws;

    float* P      = ws + P_OFF;
    float* offs   = ws + OFFS_OFF;
    unsigned short* wA_reg = (unsigned short*)(ws + WAREG_OFF);
    unsigned short* wA_off = (unsigned short*)(ws + WAOFF_OFF);

    prep_kernel<<<144, 256, 0, stream>>>(w_reg, w_off, wA_reg, wA_off);
    pad_kernel<<<(BB * 16 * PHW + 255) / 256, 256, 0, stream>>>(x, P);
    offset_conv_kernel<<<1024, 256, 0, stream>>>(P, wA_off, b_off, offs);
    deform_main_kernel<<<1024, 256, 0, stream>>>(P, offs, wA_reg, b_reg, out);
}

// Round 8
// 191.224 us; speedup vs baseline: 3.9211x; 1.0836x over previous
//
#include <hip/hip_runtime.h>
#include <math.h>

#define HH 128
#define WW 128
#define CC 64
#define BB 8
#define OC 64
#define OFFC 18
#define HW (HH*WW)
#define HP 136
#define WP 136
#define PHW (HP*WP)   /* 18496 */

typedef __attribute__((ext_vector_type(8))) short bf16x8;
typedef __attribute__((ext_vector_type(4))) float f32x4;

// ws layout (floats):
//   P4:     8*16*PHW*4 = 9469952  channel-interleaved zero-padded x
//   offs:   8*18*128*128 = 2359296
//   wA_reg: 36864 bf16 (18432 fl) A-frag [(tap*2+kk)*64+o][quad][8j]
//   wA_off: 18432 bf16 (9216 fl)  [(tap*2+kk)*32+o][quad][8j], rows 18..31 zero
#define P_OFF      0
#define P_SIZE     (BB*CC*PHW)
#define OFFS_OFF   (P_OFF + P_SIZE)
#define OFFS_SIZE  (BB*OFFC*HW)
#define WAREG_OFF  (OFFS_OFF + OFFS_SIZE)
#define WAREG_SIZE 18432
#define WAOFF_OFF  (WAREG_OFF + WAREG_SIZE)

__device__ __forceinline__ unsigned bf16rne(float f) {
    unsigned u = __float_as_uint(f);
    return (u + 0x7FFFu + ((u >> 16) & 1u)) >> 16;
}
__device__ __forceinline__ unsigned pack2(float a, float b) {
    return bf16rne(a) | (bf16rne(b) << 16);
}

__global__ __launch_bounds__(256) void prep_kernel(
    const float* __restrict__ w_reg, const float* __restrict__ w_off,
    unsigned short* __restrict__ wA_reg, unsigned short* __restrict__ wA_off)
{
    int i = blockIdx.x * 256 + threadIdx.x;
    if (i < 18 * 64 * 32) {
        int j = i & 7, quad = (i >> 3) & 3, o = (i >> 5) & 63, ks = i >> 11;
        int kt = ks >> 1, kk = ks & 1;
        int c = kk * 32 + quad * 8 + j;
        wA_reg[i] = (unsigned short)bf16rne(w_reg[o * 576 + c * 9 + kt]);
    }
    if (i < 18 * 32 * 32) {
        int j = i & 7, quad = (i >> 3) & 3, o = (i >> 5) & 31, ks = i >> 10;
        int kt = ks >> 1, kk = ks & 1;
        int c = kk * 32 + quad * 8 + j;
        float v = (o < OFFC) ? w_off[(o * CC + c) * 9 + kt] : 0.0f;
        wA_off[i] = (unsigned short)bf16rne(v);
    }
}

__global__ __launch_bounds__(256) void pad_kernel(
    const float* __restrict__ x, float* __restrict__ P)
{
    int idx = blockIdx.x * 256 + threadIdx.x;
    if (idx >= BB * 16 * PHW) return;
    int pos = idx % PHW;
    int qc  = idx / PHW;
    int r   = pos / WP;
    int col = pos % WP;
    float4 v = make_float4(0.f, 0.f, 0.f, 0.f);
    if (r >= 4 && r <= 131 && col >= 4 && col <= 131) {
        const float* src = x + (qc * 4) * HW + (r - 4) * WW + (col - 4);
        v.x = src[0];
        v.y = src[HW];
        v.z = src[2 * HW];
        v.w = src[3 * HW];
    }
    ((float4*)P)[idx] = v;
}

// Offset conv: stage the full 3-row x 130-col x 64-ch bf16 strip ONCE
// (integer taps!), one barrier, then 72 back-to-back MFMAs on shifted views.
// Block = 256 thr = one 128-px row. LDS 50.7 KB -> 3 blocks/CU.
__global__ __launch_bounds__(256) void offset_conv_kernel(
    const float* __restrict__ P, const unsigned short* __restrict__ wA_off,
    const float* __restrict__ b_off, float* __restrict__ offs)
{
    __shared__ uint4 xs[3 * 8 * 132];          // [r(3)][g(8)][j(132)] 8ch bf16
    int img  = blockIdx.x & 7;
    int pblk = blockIdx.x >> 3;                // row hv
    int tid  = threadIdx.x;
    const float4* P4 = (const float4*)P + img * 16 * PHW;
    const bf16x8* wAv = (const bf16x8*)wA_off;
    int lane = tid & 63;
    int wvid = tid >> 6;
    int s  = wvid & 1;                         // o-strip
    int ph = wvid >> 1;                        // px half

    // stage rows hv-1..hv+1, cols -1..128 (padded P -> no branches)
    for (int i = tid; i < 3 * 8 * 130; i += 256) {
        int r   = i / 1040;
        int rem = i - r * 1040;
        int g   = rem / 130;
        int j   = rem - g * 130;
        int pos = (pblk + 3 + r) * WP + (j + 3);
        float4 a = P4[(2 * g) * PHW + pos];
        float4 b = P4[(2 * g + 1) * PHW + pos];
        xs[(r * 8 + g) * 132 + j] =
            make_uint4(pack2(a.x, a.y), pack2(a.z, a.w),
                       pack2(b.x, b.y), pack2(b.z, b.w));
    }
    __syncthreads();

    f32x4 acc[4];
    #pragma unroll
    for (int pt = 0; pt < 4; ++pt) acc[pt] = (f32x4){0.f, 0.f, 0.f, 0.f};

    const bf16x8* xsv = (const bf16x8*)xs;
    for (int tap = 0; tap < 9; ++tap) {
        int dy = tap / 3, dx = tap % 3;        // row r=dy, col j = px + dx
        bf16x8 a0 = wAv[((tap * 2 + 0) * 32 + s * 16 + (lane & 15)) * 4 + (lane >> 4)];
        bf16x8 a1 = wAv[((tap * 2 + 1) * 32 + s * 16 + (lane & 15)) * 4 + (lane >> 4)];
        #pragma unroll
        for (int pt = 0; pt < 4; ++pt) {
            int j = ph * 64 + pt * 16 + (lane & 15) + dx;
            bf16x8 b0 = xsv[(dy * 8 + (lane >> 4)) * 132 + j];
            acc[pt] = __builtin_amdgcn_mfma_f32_16x16x32_bf16(a0, b0, acc[pt], 0, 0, 0);
            bf16x8 b1 = xsv[(dy * 8 + 4 + (lane >> 4)) * 132 + j];
            acc[pt] = __builtin_amdgcn_mfma_f32_16x16x32_bf16(a1, b1, acc[pt], 0, 0, 0);
        }
    }

    float* ob = offs + img * (OFFC * HW) + pblk * 128;
    #pragma unroll
    for (int r = 0; r < 4; ++r) {
        int o = s * 16 + (lane >> 4) * 4 + r;
        if (o < OFFC) {
            float bias = b_off[o];
            #pragma unroll
            for (int pt = 0; pt < 4; ++pt) {
                int pxl = ph * 64 + pt * 16 + (lane & 15);
                ob[o * HW + pxl] = acc[pt][r] + bias;
            }
        }
    }
}

// Deform: block = 256 thr = 64 px (4 thr/px, 4 quads each). 2048 blocks ->
// 8 blocks/CU. Ping-pong LDS (2x 8KB = 2x 1024 uint2) -> ONE barrier per tap.
// R7 bug was (tap&1)*2048 (whole-array overrun for odd taps); stride is 1024.
__global__ __launch_bounds__(256) void deform_main_kernel(
    const float* __restrict__ P, const float* __restrict__ offs,
    const unsigned short* __restrict__ wA_reg, const float* __restrict__ b_reg,
    float* __restrict__ out)
{
    __shared__ uint2 xs2[2 * 8 * 64 * 2];      // 16 KB: [buf][g(8)][px(64)][q&1]
    int img  = blockIdx.x & 7;
    int rest = blockIdx.x >> 3;                // 0..255
    int half = rest & 1;
    int pblk = rest >> 1;                      // row 0..127
    int tid  = threadIdx.x;
    int pxl  = tid & 63;                       // local px
    int qp   = tid >> 6;                       // quad group 0..3
    int wv = half * 64 + pxl;
    int hv = pblk;
    const float4* P4  = (const float4*)P + img * 16 * PHW;
    const float*  obf = offs + img * (OFFC * HW) + hv * WW + wv;
    const bf16x8* wAv = (const bf16x8*)wA_reg;
    int lane = tid & 63;
    int wvid = tid >> 6;                       // o-strip = wvid*16
    const float scale = 129.0f / 127.0f;

    f32x4 acc[4];
    #pragma unroll
    for (int pt = 0; pt < 4; ++pt) acc[pt] = (f32x4){0.f, 0.f, 0.f, 0.f};

    float offx = obf[0];
    float offy = obf[HW];

    for (int tap = 0; tap < 9; ++tap) {
        // prefetch next tap's offsets + this tap's A-frags (independent of staging)
        float offx_n = 0.f, offy_n = 0.f;
        if (tap < 8) {
            offx_n = obf[(2 * tap + 2) * HW];
            offy_n = obf[(2 * tap + 3) * HW];
        }
        bf16x8 a0 = wAv[((tap * 2 + 0) * 64 + wvid * 16 + (lane & 15)) * 4 + (lane >> 4)];
        bf16x8 a1 = wAv[((tap * 2 + 1) * 64 + wvid * 16 + (lane & 15)) * 4 + (lane >> 4)];

        float pxf = (float)wv + (float)(tap % 3 - 1) + offx;
        float pyf = (float)hv + (float)(tap / 3 - 1) + offy;
        float qx = fminf(fmaxf(pxf * scale, -100.0f), 300.0f);
        float qy = fminf(fmaxf(pyf * scale, -100.0f), 300.0f);
        float x0f = floorf(qx), y0f = floorf(qy);
        float wx1 = qx - x0f, wy1 = qy - y0f;
        float wx0 = 1.0f - wx1, wy0 = 1.0f - wy1;
        int ix0 = (int)x0f, iy0 = (int)y0f;
        int c0 = min(max(ix0 + 3, 0), WP - 2);
        int r0 = min(max(iy0 + 3, 0), HP - 1);
        int r1 = min(max(iy0 + 4, 0), HP - 1);
        float w00 = wy0 * wx0, w01 = wy0 * wx1;
        float w10 = wy1 * wx0, w11 = wy1 * wx1;
        int pr0 = r0 * WP + c0, pr1 = r1 * WP + c0;

        uint2* dst = xs2 + (tap & 1) * 1024;
        #pragma unroll 2
        for (int qi = 0; qi < 4; ++qi) {
            int q = qp * 4 + qi;
            const float4* xq = P4 + q * PHW;
            float4 v00 = xq[pr0];
            float4 v01 = xq[pr0 + 1];
            float4 v10 = xq[pr1];
            float4 v11 = xq[pr1 + 1];
            float s0 = w00 * v00.x; s0 = fmaf(w01, v01.x, s0);
            s0 = fmaf(w10, v10.x, s0); s0 = fmaf(w11, v11.x, s0);
            float s1 = w00 * v00.y; s1 = fmaf(w01, v01.y, s1);
            s1 = fmaf(w10, v10.y, s1); s1 = fmaf(w11, v11.y, s1);
            float s2 = w00 * v00.z; s2 = fmaf(w01, v01.z, s2);
            s2 = fmaf(w10, v10.z, s2); s2 = fmaf(w11, v11.z, s2);
            float s3 = w00 * v00.w; s3 = fmaf(w01, v01.w, s3);
            s3 = fmaf(w10, v10.w, s3); s3 = fmaf(w11, v11.w, s3);
            dst[((q >> 1) * 64 + pxl) * 2 + (q & 1)] =
                make_uint2(pack2(s0, s1), pack2(s2, s3));
        }
        __syncthreads();

        const bf16x8* xsv = (const bf16x8*)(xs2 + (tap & 1) * 1024);
        #pragma unroll
        for (int pt = 0; pt < 4; ++pt) {
            int pxi = pt * 16 + (lane & 15);
            bf16x8 b0 = xsv[(lane >> 4) * 64 + pxi];
            acc[pt] = __builtin_amdgcn_mfma_f32_16x16x32_bf16(a0, b0, acc[pt], 0, 0, 0);
            bf16x8 b1 = xsv[(4 + (lane >> 4)) * 64 + pxi];
            acc[pt] = __builtin_amdgcn_mfma_f32_16x16x32_bf16(a1, b1, acc[pt], 0, 0, 0);
        }
        offx = offx_n;
        offy = offy_n;
    }

    float* op = out + img * (OC * HW) + hv * WW + half * 64;
    #pragma unroll
    for (int r = 0; r < 4; ++r) {
        int o = wvid * 16 + (lane >> 4) * 4 + r;
        float bias = b_reg[o];
        #pragma unroll
        for (int pt = 0; pt < 4; ++pt)
            op[o * HW + pt * 16 + (lane & 15)] = acc[pt][r] + bias;
    }
}

extern "C" void kernel_launch(void* const* d_in, const int* in_sizes, int n_in,
                              void* d_out, int out_size, void* d_ws, size_t ws_size,
                              hipStream_t stream) {
    const float* x     = (const float*)d_in[0];
    const float* w_off = (const float*)d_in[1];
    const float* b_off = (const float*)d_in[2];
    const float* w_reg = (const float*)d_in[3];
    const float* b_reg = (const float*)d_in[4];
    float* out = (float*)d_out;
    float* ws  = (float*)d_ws;

    float* P      = ws + P_OFF;
    float* offs   = ws + OFFS_OFF;
    unsigned short* wA_reg = (unsigned short*)(ws + WAREG_OFF);
    unsigned short* wA_off = (unsigned short*)(ws + WAOFF_OFF);

    prep_kernel<<<144, 256, 0, stream>>>(w_reg, w_off, wA_reg, wA_off);
    pad_kernel<<<(BB * 16 * PHW + 255) / 256, 256, 0, stream>>>(x, P);
    offset_conv_kernel<<<1024, 256, 0, stream>>>(P, wA_off, b_off, offs);
    deform_main_kernel<<<2048, 256, 0, stream>>>(P, offs, wA_reg, b_reg, out);
}

// Round 9
// 155.453 us; speedup vs baseline: 4.8233x; 1.2301x over previous
//
#include <hip/hip_runtime.h>
#include <math.h>

#define HH 128
#define WW 128
#define CC 64
#define BB 8
#define OC 64
#define OFFC 18
#define HW (HH*WW)
#define HP 136
#define WP 136
#define PHW (HP*WP)   /* 18496 */

typedef __attribute__((ext_vector_type(8))) _Float16 f16x8;
typedef __attribute__((ext_vector_type(4))) float f32x4;

// ws layout (floats):
//   P16:    8 img * 8 groups * PHW uint4 (8 fp16 ch each) = BB*32*PHW floats
//   offs:   8*18*128*128 = 2359296 (fp32)
//   wA_reg: 36864 fp16 (18432 fl) A-frag [(tap*2+kk)*64+o][quad][8j]
//   wA_off: 18432 fp16 (9216 fl)  [(tap*2+kk)*32+o][quad][8j], rows 18..31 zero
#define P_OFF      0
#define P_SIZE     (BB*32*PHW)
#define OFFS_OFF   (P_OFF + P_SIZE)
#define OFFS_SIZE  (BB*OFFC*HW)
#define WAREG_OFF  (OFFS_OFF + OFFS_SIZE)
#define WAREG_SIZE 18432
#define WAOFF_OFF  (WAREG_OFF + WAREG_SIZE)

__device__ __forceinline__ unsigned short f2h(float f) {
    _Float16 t = (_Float16)f;
    unsigned short s;
    __builtin_memcpy(&s, &t, 2);
    return s;
}
__device__ __forceinline__ f16x8 u4_to_h8(uint4 u) {
    union { uint4 u; f16x8 h; } c; c.u = u; return c.h;
}
__device__ __forceinline__ uint4 h8_to_u4(f16x8 h) {
    union { uint4 u; f16x8 h; } c; c.h = h; return c.u;
}
__device__ __forceinline__ f16x8 splat8(float f) {
    _Float16 t = (_Float16)f;
    return (f16x8){t, t, t, t, t, t, t, t};
}

__global__ __launch_bounds__(256) void prep_kernel(
    const float* __restrict__ w_reg, const float* __restrict__ w_off,
    unsigned short* __restrict__ wA_reg, unsigned short* __restrict__ wA_off)
{
    int i = blockIdx.x * 256 + threadIdx.x;
    if (i < 18 * 64 * 32) {
        int j = i & 7, quad = (i >> 3) & 3, o = (i >> 5) & 63, ks = i >> 11;
        int kt = ks >> 1, kk = ks & 1;
        int c = kk * 32 + quad * 8 + j;
        wA_reg[i] = f2h(w_reg[o * 576 + c * 9 + kt]);
    }
    if (i < 18 * 32 * 32) {
        int j = i & 7, quad = (i >> 3) & 3, o = (i >> 5) & 31, ks = i >> 10;
        int kt = ks >> 1, kk = ks & 1;
        int c = kk * 32 + quad * 8 + j;
        float v = (o < OFFC) ? w_off[(o * CC + c) * 9 + kt] : 0.0f;
        wA_off[i] = f2h(v);
    }
}

// Zero-padded fp16 P: uint4 at [(img*8+g)*PHW + r*WP + col] = channels g*8..g*8+7.
__global__ __launch_bounds__(256) void pad_kernel(
    const float* __restrict__ x, uint4* __restrict__ P)
{
    int idx = blockIdx.x * 256 + threadIdx.x;     // over BB*8*PHW = 1183744
    if (idx >= BB * 8 * PHW) return;
    int pos = idx % PHW;
    int ig  = idx / PHW;          // img*8 + g
    int r   = pos / WP;
    int col = pos % WP;
    union { uint4 u; f16x8 h; } cv;
    cv.u = make_uint4(0u, 0u, 0u, 0u);
    if (r >= 4 && r <= 131 && col >= 4 && col <= 131) {
        const float* src = x + (ig * 8) * HW + (r - 4) * WW + (col - 4);
        #pragma unroll
        for (int e = 0; e < 8; ++e)
            cv.h[e] = (_Float16)src[e * HW];
    }
    P[idx] = cv.u;
}

// Offset conv: stage full 3-row x 130-col x 64-ch fp16 strip (pure uint4 copy),
// one barrier, 72 back-to-back f16 MFMAs on shifted views.
__global__ __launch_bounds__(256) void offset_conv_kernel(
    const uint4* __restrict__ P, const unsigned short* __restrict__ wA_off,
    const float* __restrict__ b_off, float* __restrict__ offs)
{
    __shared__ uint4 xs[3 * 8 * 132];          // [r(3)][g(8)][j(132)] 8ch fp16
    int img  = blockIdx.x & 7;
    int pblk = blockIdx.x >> 3;                // row hv
    int tid  = threadIdx.x;
    const f16x8* wAv = (const f16x8*)wA_off;
    int lane = tid & 63;
    int wvid = tid >> 6;
    int s  = wvid & 1;                         // o-strip
    int ph = wvid >> 1;                        // px half

    for (int i = tid; i < 3 * 8 * 130; i += 256) {
        int r   = i / 1040;
        int rem = i - r * 1040;
        int g   = rem / 130;
        int j   = rem - g * 130;
        xs[(r * 8 + g) * 132 + j] =
            P[(img * 8 + g) * PHW + (pblk + 3 + r) * WP + (j + 3)];
    }
    __syncthreads();

    f32x4 acc[4];
    #pragma unroll
    for (int pt = 0; pt < 4; ++pt) acc[pt] = (f32x4){0.f, 0.f, 0.f, 0.f};

    const f16x8* xsv = (const f16x8*)xs;
    for (int tap = 0; tap < 9; ++tap) {
        int dy = tap / 3, dx = tap % 3;
        f16x8 a0 = wAv[((tap * 2 + 0) * 32 + s * 16 + (lane & 15)) * 4 + (lane >> 4)];
        f16x8 a1 = wAv[((tap * 2 + 1) * 32 + s * 16 + (lane & 15)) * 4 + (lane >> 4)];
        #pragma unroll
        for (int pt = 0; pt < 4; ++pt) {
            int j = ph * 64 + pt * 16 + (lane & 15) + dx;
            f16x8 b0 = xsv[(dy * 8 + (lane >> 4)) * 132 + j];
            acc[pt] = __builtin_amdgcn_mfma_f32_16x16x32_f16(a0, b0, acc[pt], 0, 0, 0);
            f16x8 b1 = xsv[(dy * 8 + 4 + (lane >> 4)) * 132 + j];
            acc[pt] = __builtin_amdgcn_mfma_f32_16x16x32_f16(a1, b1, acc[pt], 0, 0, 0);
        }
    }

    float* ob = offs + img * (OFFC * HW) + pblk * 128;
    #pragma unroll
    for (int r = 0; r < 4; ++r) {
        int o = s * 16 + (lane >> 4) * 4 + r;
        if (o < OFFC) {
            float bias = b_off[o];
            #pragma unroll
            for (int pt = 0; pt < 4; ++pt) {
                int pxl = ph * 64 + pt * 16 + (lane & 15);
                ob[o * HW + pxl] = acc[pt][r] + bias;
            }
        }
    }
}

// Deform: block = 256 thr = 64 px (4 thr/px, 2 8-ch groups each).
// fp16 P: 8 uint4 gathers/thread/tap; bilinear in packed fp16 (v_pk_fma_f16);
// ping-pong LDS (2x512 uint4), one barrier per tap.
__global__ __launch_bounds__(256) void deform_main_kernel(
    const uint4* __restrict__ P, const float* __restrict__ offs,
    const unsigned short* __restrict__ wA_reg, const float* __restrict__ b_reg,
    float* __restrict__ out)
{
    __shared__ uint4 xs2[2 * 512];             // 16 KB: [buf][g(8)][px(64)]
    int img  = blockIdx.x & 7;
    int rest = blockIdx.x >> 3;                // 0..255
    int half = rest & 1;
    int pblk = rest >> 1;                      // row 0..127
    int tid  = threadIdx.x;
    int pxl  = tid & 63;                       // local px
    int qp   = tid >> 6;                       // group pair 0..3
    int wv = half * 64 + pxl;
    int hv = pblk;
    const float*  obf = offs + img * (OFFC * HW) + hv * WW + wv;
    const f16x8*  wAv = (const f16x8*)wA_reg;
    int lane = tid & 63;
    int wvid = tid >> 6;                       // o-strip = wvid*16
    const float scale = 129.0f / 127.0f;

    f32x4 acc[4];
    #pragma unroll
    for (int pt = 0; pt < 4; ++pt) acc[pt] = (f32x4){0.f, 0.f, 0.f, 0.f};

    float offx = obf[0];
    float offy = obf[HW];

    for (int tap = 0; tap < 9; ++tap) {
        float offx_n = 0.f, offy_n = 0.f;
        if (tap < 8) {
            offx_n = obf[(2 * tap + 2) * HW];
            offy_n = obf[(2 * tap + 3) * HW];
        }
        f16x8 a0 = wAv[((tap * 2 + 0) * 64 + wvid * 16 + (lane & 15)) * 4 + (lane >> 4)];
        f16x8 a1 = wAv[((tap * 2 + 1) * 64 + wvid * 16 + (lane & 15)) * 4 + (lane >> 4)];

        float pxf = (float)wv + (float)(tap % 3 - 1) + offx;
        float pyf = (float)hv + (float)(tap / 3 - 1) + offy;
        float qx = fminf(fmaxf(pxf * scale, -100.0f), 300.0f);
        float qy = fminf(fmaxf(pyf * scale, -100.0f), 300.0f);
        float x0f = floorf(qx), y0f = floorf(qy);
        float wx1 = qx - x0f, wy1 = qy - y0f;
        float wx0 = 1.0f - wx1, wy0 = 1.0f - wy1;
        int ix0 = (int)x0f, iy0 = (int)y0f;
        int c0 = min(max(ix0 + 3, 0), WP - 2);
        int r0 = min(max(iy0 + 3, 0), HP - 1);
        int r1 = min(max(iy0 + 4, 0), HP - 1);
        int pr0 = r0 * WP + c0, pr1 = r1 * WP + c0;

        f16x8 wx0v = splat8(wx0), wx1v = splat8(wx1);
        f16x8 wy0v = splat8(wy0), wy1v = splat8(wy1);

        uint4* dst = xs2 + (tap & 1) * 512;
        #pragma unroll
        for (int gi = 0; gi < 2; ++gi) {
            int g = qp * 2 + gi;
            const uint4* xq = P + (img * 8 + g) * PHW;
            f16x8 v00 = u4_to_h8(xq[pr0]);
            f16x8 v01 = u4_to_h8(xq[pr0 + 1]);
            f16x8 v10 = u4_to_h8(xq[pr1]);
            f16x8 v11 = u4_to_h8(xq[pr1 + 1]);
            f16x8 row0 = v00 * wx0v + v01 * wx1v;
            f16x8 row1 = v10 * wx0v + v11 * wx1v;
            f16x8 sv   = row0 * wy0v + row1 * wy1v;
            dst[g * 64 + pxl] = h8_to_u4(sv);
        }
        __syncthreads();

        const f16x8* xsv = (const f16x8*)(xs2 + (tap & 1) * 512);
        #pragma unroll
        for (int pt = 0; pt < 4; ++pt) {
            int pxi = pt * 16 + (lane & 15);
            f16x8 b0 = xsv[(lane >> 4) * 64 + pxi];
            acc[pt] = __builtin_amdgcn_mfma_f32_16x16x32_f16(a0, b0, acc[pt], 0, 0, 0);
            f16x8 b1 = xsv[(4 + (lane >> 4)) * 64 + pxi];
            acc[pt] = __builtin_amdgcn_mfma_f32_16x16x32_f16(a1, b1, acc[pt], 0, 0, 0);
        }
        offx = offx_n;
        offy = offy_n;
    }

    float* op = out + img * (OC * HW) + hv * WW + half * 64;
    #pragma unroll
    for (int r = 0; r < 4; ++r) {
        int o = wvid * 16 + (lane >> 4) * 4 + r;
        float bias = b_reg[o];
        #pragma unroll
        for (int pt = 0; pt < 4; ++pt)
            op[o * HW + pt * 16 + (lane & 15)] = acc[pt][r] + bias;
    }
}

extern "C" void kernel_launch(void* const* d_in, const int* in_sizes, int n_in,
                              void* d_out, int out_size, void* d_ws, size_t ws_size,
                              hipStream_t stream) {
    const float* x     = (const float*)d_in[0];
    const float* w_off = (const float*)d_in[1];
    const float* b_off = (const float*)d_in[2];
    const float* w_reg = (const float*)d_in[3];
    const float* b_reg = (const float*)d_in[4];
    float* out = (float*)d_out;
    float* ws  = (float*)d_ws;

    uint4* P      = (uint4*)(ws + P_OFF);
    float* offs   = ws + OFFS_OFF;
    unsigned short* wA_reg = (unsigned short*)(ws + WAREG_OFF);
    unsigned short* wA_off = (unsigned short*)(ws + WAOFF_OFF);

    prep_kernel<<<144, 256, 0, stream>>>(w_reg, w_off, wA_reg, wA_off);
    pad_kernel<<<(BB * 8 * PHW + 255) / 256, 256, 0, stream>>>(x, P);
    offset_conv_kernel<<<1024, 256, 0, stream>>>(P, wA_off, b_off, offs);
    deform_main_kernel<<<2048, 256, 0, stream>>>(P, offs, wA_reg, b_reg, out);
}